// Round 9
// baseline (110.692 us; speedup 1.0000x reference)
//
#include <hip/hip_runtime.h>

#define VOCAB 4096
#define SLICES 16
#define SLICE 256            // codes per slice (16-way split per point)
#define GRP 8                // codes per min-tree group
#define NGRP (SLICE / GRP)   // 32 groups per slice

// Empty-asm register barrier: forces the value into a VGPR, preventing
// fma-contraction / reassociation across it. Emits no instruction.
__device__ __forceinline__ float opaque(float x) {
  asm volatile("" : "+v"(x));
  return x;
}

// v_min3_f32: value-identical to fminf(fminf(a,b),c) for finite inputs
// (min is exact; no rounding). Compiler won't form min3 without nnan.
__device__ __forceinline__ float min3(float a, float b, float c) {
  float d;
  asm("v_min3_f32 %0, %1, %2, %3" : "=v"(d) : "v"(a), "v"(b), "v"(c));
  return d;
}

// Prep: pack per-code {e0, e1, e2, ||e||^2_f32} into ws as float4, where
// ||e||^2 is rounded exactly like numpy: ((e0*e0 + e1*e1) + e2*e2), each
// product and sum individually rounded in f32. Also zero the loss slot.
__global__ __launch_bounds__(256) void vq_prep_kernel(
    const float* __restrict__ cb, float4* __restrict__ cw,
    float* __restrict__ loss_slot) {
  int j = blockIdx.x * 256 + threadIdx.x;
  if (j == 0) *loss_slot = 0.0f;
  if (j < VOCAB) {
    float e0 = cb[3 * j + 0];
    float e1 = cb[3 * j + 1];
    float e2 = cb[3 * j + 2];
    float p0 = opaque(e0 * e0);
    float p1 = opaque(e1 * e1);
    float p2 = opaque(e2 * e2);
    float c = opaque(opaque(p0 + p1) + p2);
    cw[j] = make_float4(e0, e1, e2, c);
  }
}

// Distance with numpy's exact f32 rounding:
//   m = x.e (fma ascending k, first term single-rounded mul)
//   d = (a - 2m) + c   [a-2m via fma(-2,m,a): 2m is exact, value-identical]
__device__ __forceinline__ float dist_f32(float x0, float x1, float x2,
                                          float a, float4 cd) {
  float m = fmaf(x2, cd.z, fmaf(x1, cd.y, x0 * cd.x));
  return fmaf(-2.0f, m, a) + cd.w;
}

// Main: block = 1024 threads = 64 points x 16 codebook slices.
// 1024 blocks x 16 waves = 16384 waves; 2 blocks/CU co-resident
// -> 8 waves/SIMD steady-state for SMEM latency hiding.
__global__ __launch_bounds__(1024) void vq_kernel(
    const float* __restrict__ feats, const float4* __restrict__ cw,
    float* __restrict__ out_quant, float* __restrict__ out_idx,
    float* __restrict__ out_loss, int npts) {
  __shared__ float sB[1024];
  __shared__ int sI[1024];
  __shared__ double sL[64];

  const int tid = threadIdx.x;
  const int lane = tid & 63;
  // slice id is wave-uniform; force SGPR so code records stream via s_load
  const int s = __builtin_amdgcn_readfirstlane(tid >> 6);
  const int p = blockIdx.x * 64 + lane;

  const float x0 = feats[3 * p + 0];
  const float x1 = feats[3 * p + 1];
  const float x2 = feats[3 * p + 2];

  // ||x||^2 exactly as numpy: products rounded, then ((p0+p1)+p2)
  float xp0 = opaque(x0 * x0);
  float xp1 = opaque(x1 * x1);
  float xp2 = opaque(x2 * x2);
  const float a = opaque(opaque(xp0 + xp1) + xp2);

  const float4* cs = cw + s * SLICE;

  // Group-min scan: track only (best value, winning group base).
  // All distances are >= (|x|-|e|)^2 >> 0: positive, no NaN -> min exact.
  float best = 3.4e38f;
  int gbase = 0;
#pragma unroll 2
  for (int g = 0; g < NGRP; ++g) {
    const float4* gp = cs + g * GRP;  // wave-uniform -> s_load_dwordx16 x2
    float d0 = dist_f32(x0, x1, x2, a, gp[0]);
    float d1 = dist_f32(x0, x1, x2, a, gp[1]);
    float d2 = dist_f32(x0, x1, x2, a, gp[2]);
    float d3 = dist_f32(x0, x1, x2, a, gp[3]);
    float d4 = dist_f32(x0, x1, x2, a, gp[4]);
    float d5 = dist_f32(x0, x1, x2, a, gp[5]);
    float d6 = dist_f32(x0, x1, x2, a, gp[6]);
    float d7 = dist_f32(x0, x1, x2, a, gp[7]);
    // 8-way min in 4 insts via v_min3; value == nested fminf tree
    float gm = min3(min3(d0, d1, d2), min3(d3, d4, d5), fminf(d6, d7));
    // strict <: keeps the EARLIEST group attaining the running min
    if (gm < best) gbase = g;
    best = fminf(best, gm);
  }
  gbase = s * SLICE + gbase * GRP;

  sB[tid] = best;
  sI[tid] = gbase;
  __syncthreads();

  if (tid < 64) {
    // combine slices in ascending-index order; strict < keeps earliest group
#pragma unroll
    for (int k = 1; k < SLICES; ++k) {
      float v = sB[tid + 64 * k];
      if (v < best) { best = v; gbase = sI[tid + 64 * k]; }
    }
    // Index recovery: rescan the winning 8-code group with identical
    // rounding; ascending, strict <: np.argmin's first-occurrence winner.
    int bi = gbase;
    float bd = 3.4e38f;
    float q0 = 0.0f, q1 = 0.0f, q2 = 0.0f;
#pragma unroll
    for (int k = 0; k < GRP; ++k) {
      float4 cd = cw[gbase + k];
      float d = dist_f32(x0, x1, x2, a, cd);
      if (d < bd) { bd = d; bi = gbase + k; q0 = cd.x; q1 = cd.y; q2 = cd.z; }
    }
    // straight-through: t = q - x (f32), out = x + t (f32), like reference
    float t0 = q0 - x0, t1 = q1 - x1, t2 = q2 - x2;
    out_quant[3 * p + 0] = x0 + t0;
    out_quant[3 * p + 1] = x1 + t1;
    out_quant[3 * p + 2] = x2 + t2;
    out_idx[p] = (float)bi;
    sL[tid] = (double)t0 * t0 + (double)t1 * t1 + (double)t2 * t2;
  }
  __syncthreads();

  if (tid == 0) {
    double acc = 0.0;
#pragma unroll 8
    for (int k = 0; k < 64; ++k) acc += sL[k];
    // loss = mean((q-x)^2) + 0.25*mean((x-q)^2) = 1.25 * sum / (npts*3)
    atomicAdd(out_loss, (float)(acc * (1.25 / ((double)npts * 3.0))));
  }
}

extern "C" void kernel_launch(void* const* d_in, const int* in_sizes, int n_in,
                              void* d_out, int out_size, void* d_ws,
                              size_t ws_size, hipStream_t stream) {
  const float* feats = (const float*)d_in[0];      // (B*L, 3) f32
  const float* cb = (const float*)d_in[1];         // (4096, 3) f32
  const int npts = in_sizes[0] / 3;                // 65536

  float* out = (float*)d_out;
  float* out_quant = out;                          // npts*3 elems
  float* out_idx = out + in_sizes[0];              // npts elems
  float* out_loss = out + in_sizes[0] + npts;      // 1 elem

  float4* cw = (float4*)d_ws;                      // 4096 * 16 B = 64 KB

  vq_prep_kernel<<<VOCAB / 256, 256, 0, stream>>>(cb, cw, out_loss);
  vq_kernel<<<npts / 64, 1024, 0, stream>>>(feats, cw, out_quant, out_idx,
                                            out_loss, npts);
}

// Round 10
// 108.103 us; speedup vs baseline: 1.0239x; 1.0239x over previous
//
#include <hip/hip_runtime.h>

#define VOCAB 4096
#define SLICES 8
#define SLICE 512            // codes per slice (8-way split per point)
#define GRP 8                // codes per max-tree group
#define NGRP (SLICE / GRP)   // 64 groups per slice

// Empty-asm register barrier: forces the value into a VGPR, preventing
// fma-contraction / reassociation across it. Emits no instruction.
__device__ __forceinline__ float opaque(float x) {
  asm volatile("" : "+v"(x));
  return x;
}

// v_max3_f32: value-identical to nested fmaxf for finite inputs (max is
// exact). Compiler won't form max3 without nnan, so emit directly.
__device__ __forceinline__ float max3f(float a, float b, float c) {
  float d;
  asm("v_max3_f32 %0, %1, %2, %3" : "=v"(d) : "v"(a), "v"(b), "v"(c));
  return d;
}

// Prep: pack per-code {e0, e1, e2, h} where h = -0.5f*c and
// c = ((e0*e0+e1*e1)+e2*e2) rounded exactly like numpy (each product/sum
// individually rounded f32). h is an exact scale of c (exponent shift),
// so c = -2*h is recoverable bit-exactly. Also zero the loss slot.
__global__ __launch_bounds__(256) void vq_prep_kernel(
    const float* __restrict__ cb, float4* __restrict__ cw,
    float* __restrict__ loss_slot) {
  int j = blockIdx.x * 256 + threadIdx.x;
  if (j == 0) *loss_slot = 0.0f;
  if (j < VOCAB) {
    float e0 = cb[3 * j + 0];
    float e1 = cb[3 * j + 1];
    float e2 = cb[3 * j + 2];
    float p0 = opaque(e0 * e0);
    float p1 = opaque(e1 * e1);
    float p2 = opaque(e2 * e2);
    float c = opaque(opaque(p0 + p1) + p2);
    cw[j] = make_float4(e0, e1, e2, -0.5f * c);
  }
}

// Surrogate scan value: t = x.e - c/2 (3 fma). Exact relation: a - 2T = D.
// argmin d == argmax t, up to rounding noise covered by the margin eps.
__device__ __forceinline__ float tval(float x0, float x1, float x2,
                                      float4 cd) {
  return fmaf(x0, cd.x, fmaf(x1, cd.y, fmaf(x2, cd.z, cd.w)));
}

// Bit-exact numpy f32 distance (validated absmax=0.0 in R6/R7/R8):
//   m = x.e (fma ascending k, first term single-rounded mul)
//   d = (a - 2m) + c;  c = -2*h exact; +(-2h) may contract to
//   fma(-2,h,·) which is value-identical since 2h is exact.
__device__ __forceinline__ float dist_f32(float x0, float x1, float x2,
                                          float a, float4 cd) {
  float m = fmaf(x2, cd.z, fmaf(x1, cd.y, x0 * cd.x));
  return fmaf(-2.0f, m, a) + (-2.0f * cd.w);
}

// Main: block = 512 threads = 64 points x 8 codebook slices.
__global__ __launch_bounds__(512) void vq_kernel(
    const float* __restrict__ feats, const float4* __restrict__ cw,
    float* __restrict__ out_quant, float* __restrict__ out_idx,
    float* __restrict__ out_loss, int npts) {
  __shared__ float sT1[512];
  __shared__ float sT2[512];
  __shared__ int sG[512];
  __shared__ unsigned long long sSlot[64];  // per-lane best (d,idx) key
  __shared__ int sList[64];                 // flagged lane ids
  __shared__ int sCount;
  __shared__ double sL[64];

  const int tid = threadIdx.x;
  const int lane = tid & 63;
  // slice id is wave-uniform; force SGPR so code records stream via s_load
  const int s = __builtin_amdgcn_readfirstlane(tid >> 6);
  const int p = blockIdx.x * 64 + lane;

  if (tid == 0) sCount = 0;

  const float x0 = feats[3 * p + 0];
  const float x1 = feats[3 * p + 1];
  const float x2 = feats[3 * p + 2];

  // ||x||^2 exactly as numpy: products rounded, then ((p0+p1)+p2)
  float xp0 = opaque(x0 * x0);
  float xp1 = opaque(x1 * x1);
  float xp2 = opaque(x2 * x2);
  const float a = opaque(opaque(xp0 + xp1) + xp2);

  const float4* cs = cw + s * SLICE;

  // Phase 1: surrogate scan. Per group of 8: max-tree over t; stream-track
  // best group (t1,g1) and second-best group-max t2 for the margin test.
  float t1 = -3.4e38f, t2 = -3.4e38f;
  int g1 = 0;
#pragma unroll 2
  for (int g = 0; g < NGRP; ++g) {
    const float4* gp = cs + g * GRP;  // wave-uniform -> s_load_dwordx16 x2
    float u0 = tval(x0, x1, x2, gp[0]);
    float u1 = tval(x0, x1, x2, gp[1]);
    float u2 = tval(x0, x1, x2, gp[2]);
    float u3 = tval(x0, x1, x2, gp[3]);
    float u4 = tval(x0, x1, x2, gp[4]);
    float u5 = tval(x0, x1, x2, gp[5]);
    float u6 = tval(x0, x1, x2, gp[6]);
    float u7 = tval(x0, x1, x2, gp[7]);
    float gm = max3f(max3f(u0, u1, u2), max3f(u3, u4, u5), fmaxf(u6, u7));
    t2 = fmaxf(t2, fminf(t1, gm));   // streaming top-2 of group maxes
    if (gm > t1) g1 = g;             // strict >: earliest group kept
    t1 = fmaxf(t1, gm);
  }
  sT1[tid] = t1;
  sT2[tid] = t2;
  sG[tid] = s * SLICE + g1 * GRP;
  __syncthreads();

  int bi = 0;
  float q0 = 0.0f, q1 = 0.0f, q2 = 0.0f;
  bool flagged = false;
  if (tid < 64) {
    int gbase = sG[tid];
#pragma unroll
    for (int k = 1; k < SLICES; ++k) {  // ascending slice order
      float b1 = sT1[tid + 64 * k];
      float b2 = sT2[tid + 64 * k];
      t2 = fmaxf(fmaxf(t2, b2), fminf(t1, b1));
      if (b1 > t1) gbase = sG[tid + 64 * k];
      t1 = fmaxf(t1, b1);
    }
    // Margin test: if best group's t beats every other group's max by more
    // than worst-case surrogate-vs-numpy rounding skew, ref argmin is in
    // gbase. Need ~(4a*2^-24 + 5e-7); eps = a*2^-21 + 2^-20 is 2x safe.
    float eps = fmaf(a, 0x1p-21f, 0x1p-20f);
    flagged = !((t1 - t2) > eps);
    if (flagged) {
      int pos = atomicAdd(&sCount, 1);
      sList[pos] = lane;
      sSlot[lane] = ~0ULL;
    } else {
      // Bit-exact rescan of the certified 8-code group; ascending, strict
      // <: np.argmin first-occurrence.
      float bd = 3.4e38f;
#pragma unroll
      for (int k = 0; k < GRP; ++k) {
        float4 cd = cw[gbase + k];
        float d = dist_f32(x0, x1, x2, a, cd);
        if (d < bd) { bd = d; bi = gbase + k; q0 = cd.x; q1 = cd.y; q2 = cd.z; }
      }
    }
  }
  __syncthreads();

  // Phase 2: cooperative bit-exact full rescan for flagged points.
  // All 512 threads split the 4096 codes (8 each); reduce via sortable
  // (d,idx) key: min key == min d, tie -> min idx (first occurrence).
  const int cnt = sCount;
  for (int f = 0; f < cnt; ++f) {
    const int fl = sList[f];
    const int fp = blockIdx.x * 64 + fl;
    float y0 = feats[3 * fp + 0];   // same addr all threads -> broadcast
    float y1 = feats[3 * fp + 1];
    float y2 = feats[3 * fp + 2];
    float yp0 = opaque(y0 * y0);
    float yp1 = opaque(y1 * y1);
    float yp2 = opaque(y2 * y2);
    float ay = opaque(opaque(yp0 + yp1) + yp2);
    float bd = 3.4e38f;
    int bj = 0;
#pragma unroll
    for (int k = 0; k < 8; ++k) {
      float4 cd = cw[tid * 8 + k];
      float d = dist_f32(y0, y1, y2, ay, cd);
      if (d < bd) { bd = d; bj = tid * 8 + k; }
    }
    unsigned b = __float_as_uint(bd);
    b = (b & 0x80000000u) ? ~b : (b | 0x80000000u);  // total-order transform
    unsigned long long key = ((unsigned long long)b << 32) | (unsigned)bj;
#pragma unroll
    for (int off = 1; off < 64; off <<= 1) {         // wave min-butterfly
      unsigned long long o = __shfl_xor(key, off);
      key = (o < key) ? o : key;
    }
    if (lane == 0) atomicMin(&sSlot[fl], key);       // 8 atomics/point
  }
  __syncthreads();

  if (tid < 64) {
    if (flagged) {
      bi = (int)(unsigned)(sSlot[lane] & 0xFFFFFFFFu);
      float4 cd = cw[bi];
      q0 = cd.x; q1 = cd.y; q2 = cd.z;
    }
    // straight-through: t = q - x (f32), out = x + t (f32), like reference
    float t0 = q0 - x0, t1d = q1 - x1, t2d = q2 - x2;
    out_quant[3 * p + 0] = x0 + t0;
    out_quant[3 * p + 1] = x1 + t1d;
    out_quant[3 * p + 2] = x2 + t2d;
    out_idx[p] = (float)bi;
    sL[lane] = (double)t0 * t0 + (double)t1d * t1d + (double)t2d * t2d;
  }
  __syncthreads();

  if (tid == 0) {
    double acc = 0.0;
#pragma unroll 8
    for (int k = 0; k < 64; ++k) acc += sL[k];
    // loss = mean((q-x)^2) + 0.25*mean((x-q)^2) = 1.25 * sum / (npts*3)
    atomicAdd(out_loss, (float)(acc * (1.25 / ((double)npts * 3.0))));
  }
}

extern "C" void kernel_launch(void* const* d_in, const int* in_sizes, int n_in,
                              void* d_out, int out_size, void* d_ws,
                              size_t ws_size, hipStream_t stream) {
  const float* feats = (const float*)d_in[0];      // (B*L, 3) f32
  const float* cb = (const float*)d_in[1];         // (4096, 3) f32
  const int npts = in_sizes[0] / 3;                // 65536

  float* out = (float*)d_out;
  float* out_quant = out;                          // npts*3 elems
  float* out_idx = out + in_sizes[0];              // npts elems
  float* out_loss = out + in_sizes[0] + npts;      // 1 elem

  float4* cw = (float4*)d_ws;                      // 4096 * 16 B = 64 KB

  vq_prep_kernel<<<VOCAB / 256, 256, 0, stream>>>(cb, cw, out_loss);
  vq_kernel<<<npts / 64, 512, 0, stream>>>(feats, cw, out_quant, out_idx,
                                           out_loss, npts);
}

// Round 11
// 94.329 us; speedup vs baseline: 1.1735x; 1.1460x over previous
//
#include <hip/hip_runtime.h>

#define VOCAB 4096
#define SLICES 8
#define SLICE 512            // codes per slice (8-way split per point-set)
#define GRP 8                // codes per min-tree group
#define NGRP (SLICE / GRP)   // 64 groups per slice
#define PTS 128              // points per block (2 per lane)

// Empty-asm register barrier: forces the value into a VGPR, preventing
// fma-contraction / reassociation across it. Emits no instruction.
__device__ __forceinline__ float opaque(float x) {
  asm volatile("" : "+v"(x));
  return x;
}

// v_min3_f32: value-identical to nested fminf for finite inputs (min is
// exact, no rounding). Compiler won't form min3 without nnan.
__device__ __forceinline__ float min3(float a, float b, float c) {
  float d;
  asm("v_min3_f32 %0, %1, %2, %3" : "=v"(d) : "v"(a), "v"(b), "v"(c));
  return d;
}

// Prep: pack per-code {e0, e1, e2, ||e||^2_f32} into ws as float4, where
// ||e||^2 is rounded exactly like numpy: ((e0*e0 + e1*e1) + e2*e2), each
// product and sum individually rounded in f32. Also zero the loss slot.
__global__ __launch_bounds__(256) void vq_prep_kernel(
    const float* __restrict__ cb, float4* __restrict__ cw,
    float* __restrict__ loss_slot) {
  int j = blockIdx.x * 256 + threadIdx.x;
  if (j == 0) *loss_slot = 0.0f;
  if (j < VOCAB) {
    float e0 = cb[3 * j + 0];
    float e1 = cb[3 * j + 1];
    float e2 = cb[3 * j + 2];
    float p0 = opaque(e0 * e0);
    float p1 = opaque(e1 * e1);
    float p2 = opaque(e2 * e2);
    float c = opaque(opaque(p0 + p1) + p2);
    cw[j] = make_float4(e0, e1, e2, c);
  }
}

// Distance with numpy's exact f32 rounding (validated absmax=0.0 R6/R8):
//   m = x.e (fma ascending k, first term single-rounded mul)
//   d = (a - 2m) + c   [a-2m via fma(-2,m,a): 2m exact, value-identical]
__device__ __forceinline__ float dist_f32(float x0, float x1, float x2,
                                          float a, float4 cd) {
  float m = fmaf(x2, cd.z, fmaf(x1, cd.y, x0 * cd.x));
  return fmaf(-2.0f, m, a) + cd.w;
}

// Main: 512 blocks x 512 threads; block = 128 points x 8 slices.
// Codebook staged in LDS (64 KB) -> code stream leaves the SQC/K$ path.
// 2 blocks/CU (73 KB LDS) = 16 waves/CU.
__global__ __launch_bounds__(512) void vq_kernel(
    const float* __restrict__ feats, const float4* __restrict__ cw,
    float* __restrict__ out_quant, float* __restrict__ out_idx,
    float* __restrict__ out_loss, int npts) {
  __shared__ float4 sTab[VOCAB];        // 64 KB staged codebook
  __shared__ float sB[SLICES * PTS];    // 4 KB per-slice best
  __shared__ int sI[SLICES * PTS];      // 4 KB per-slice group base
  __shared__ double sL[PTS];            // 1 KB loss partials

  const int tid = threadIdx.x;
  const int lane = tid & 63;
  const int s = tid >> 6;               // slice id (wave-uniform)

  // Stage codebook: coalesced float4 copy, 8 per thread.
#pragma unroll
  for (int k = 0; k < VOCAB / 512; ++k) sTab[tid + k * 512] = cw[tid + k * 512];

  const int pbase = blockIdx.x * PTS;
  const int pA = pbase + lane;          // this lane's point 0
  const int pB = pbase + 64 + lane;     // this lane's point 1

  const float a0 = feats[3 * pA + 0], a1 = feats[3 * pA + 1],
              a2 = feats[3 * pA + 2];
  const float b0 = feats[3 * pB + 0], b1 = feats[3 * pB + 1],
              b2 = feats[3 * pB + 2];

  // ||x||^2 exactly as numpy: products rounded, then ((p0+p1)+p2)
  float ap0 = opaque(a0 * a0), ap1 = opaque(a1 * a1), ap2 = opaque(a2 * a2);
  const float na = opaque(opaque(ap0 + ap1) + ap2);
  float bp0 = opaque(b0 * b0), bp1 = opaque(b1 * b1), bp2 = opaque(b2 * b2);
  const float nb = opaque(opaque(bp0 + bp1) + bp2);

  __syncthreads();  // staging complete

  const float4* cs = sTab + s * SLICE;

  // Group-min scan over LDS-broadcast codes, 2 points per lane.
  // Distances positive, no NaN -> min exact; strict < keeps earliest group.
  float bestA = 3.4e38f, bestB = 3.4e38f;
  int gA = 0, gB = 0;
#pragma unroll 2
  for (int g = 0; g < NGRP; ++g) {
    const float4* gp = cs + g * GRP;    // same addr all lanes -> broadcast
    float4 c0 = gp[0], c1 = gp[1], c2 = gp[2], c3 = gp[3];
    float4 c4 = gp[4], c5 = gp[5], c6 = gp[6], c7 = gp[7];
    float dA0 = dist_f32(a0, a1, a2, na, c0), dB0 = dist_f32(b0, b1, b2, nb, c0);
    float dA1 = dist_f32(a0, a1, a2, na, c1), dB1 = dist_f32(b0, b1, b2, nb, c1);
    float dA2 = dist_f32(a0, a1, a2, na, c2), dB2 = dist_f32(b0, b1, b2, nb, c2);
    float dA3 = dist_f32(a0, a1, a2, na, c3), dB3 = dist_f32(b0, b1, b2, nb, c3);
    float dA4 = dist_f32(a0, a1, a2, na, c4), dB4 = dist_f32(b0, b1, b2, nb, c4);
    float dA5 = dist_f32(a0, a1, a2, na, c5), dB5 = dist_f32(b0, b1, b2, nb, c5);
    float dA6 = dist_f32(a0, a1, a2, na, c6), dB6 = dist_f32(b0, b1, b2, nb, c6);
    float dA7 = dist_f32(a0, a1, a2, na, c7), dB7 = dist_f32(b0, b1, b2, nb, c7);
    float gmA = min3(min3(dA0, dA1, dA2), min3(dA3, dA4, dA5), fminf(dA6, dA7));
    float gmB = min3(min3(dB0, dB1, dB2), min3(dB3, dB4, dB5), fminf(dB6, dB7));
    if (gmA < bestA) gA = g;
    bestA = fminf(bestA, gmA);
    if (gmB < bestB) gB = g;
    bestB = fminf(bestB, gmB);
  }
  sB[s * PTS + lane] = bestA;
  sI[s * PTS + lane] = s * SLICE + gA * GRP;
  sB[s * PTS + 64 + lane] = bestB;
  sI[s * PTS + 64 + lane] = s * SLICE + gB * GRP;
  __syncthreads();

  // Epilogue: thread tid < 128 owns block-point pt == tid, which is its own
  // pA (waves 0) or pB (wave 1) -> coords already in registers.
  if (tid < PTS) {
    const float x0 = (s == 0) ? a0 : b0;
    const float x1 = (s == 0) ? a1 : b1;
    const float x2 = (s == 0) ? a2 : b2;
    const float a = (s == 0) ? na : nb;
    float best = sB[tid];
    int gbase = sI[tid];
    // combine slices in ascending-index order; strict < keeps earliest group
#pragma unroll
    for (int k = 1; k < SLICES; ++k) {
      float v = sB[k * PTS + tid];
      if (v < best) { best = v; gbase = sI[k * PTS + tid]; }
    }
    // Index recovery: bit-exact rescan of the winning 8-code group from
    // LDS (identical data); ascending, strict <: np.argmin first-min.
    int bi = gbase;
    float bd = 3.4e38f;
    float q0 = 0.0f, q1 = 0.0f, q2 = 0.0f;
#pragma unroll
    for (int k = 0; k < GRP; ++k) {
      float4 cd = sTab[gbase + k];
      float d = dist_f32(x0, x1, x2, a, cd);
      if (d < bd) { bd = d; bi = gbase + k; q0 = cd.x; q1 = cd.y; q2 = cd.z; }
    }
    const int p = pbase + tid;
    // straight-through: t = q - x (f32), out = x + t (f32), like reference
    float t0 = q0 - x0, t1 = q1 - x1, t2 = q2 - x2;
    out_quant[3 * p + 0] = x0 + t0;
    out_quant[3 * p + 1] = x1 + t1;
    out_quant[3 * p + 2] = x2 + t2;
    out_idx[p] = (float)bi;
    sL[tid] = (double)t0 * t0 + (double)t1 * t1 + (double)t2 * t2;
  }
  __syncthreads();

  if (tid == 0) {
    double acc = 0.0;
#pragma unroll 8
    for (int k = 0; k < PTS; ++k) acc += sL[k];
    // loss = mean((q-x)^2) + 0.25*mean((x-q)^2) = 1.25 * sum / (npts*3)
    atomicAdd(out_loss, (float)(acc * (1.25 / ((double)npts * 3.0))));
  }
}

extern "C" void kernel_launch(void* const* d_in, const int* in_sizes, int n_in,
                              void* d_out, int out_size, void* d_ws,
                              size_t ws_size, hipStream_t stream) {
  const float* feats = (const float*)d_in[0];      // (B*L, 3) f32
  const float* cb = (const float*)d_in[1];         // (4096, 3) f32
  const int npts = in_sizes[0] / 3;                // 65536

  float* out = (float*)d_out;
  float* out_quant = out;                          // npts*3 elems
  float* out_idx = out + in_sizes[0];              // npts elems
  float* out_loss = out + in_sizes[0] + npts;      // 1 elem

  float4* cw = (float4*)d_ws;                      // 4096 * 16 B = 64 KB

  vq_prep_kernel<<<VOCAB / 256, 256, 0, stream>>>(cb, cw, out_loss);
  vq_kernel<<<npts / PTS, 512, 0, stream>>>(feats, cw, out_quant, out_idx,
                                            out_loss, npts);
}

// Round 12
// 92.776 us; speedup vs baseline: 1.1931x; 1.0167x over previous
//
#include <hip/hip_runtime.h>

#define VOCAB 4096
#define SLICES 8
#define SLICE 512            // codes per slice (8-way split per point-set)
#define GRP 8                // codes per max-tree group
#define NGRP (SLICE / GRP)   // 64 groups per slice
#define PTS 128              // points per block (2 per lane)

// Empty-asm register barrier: forces the value into a VGPR, preventing
// fma-contraction / reassociation across it. Emits no instruction.
__device__ __forceinline__ float opaque(float x) {
  asm volatile("" : "+v"(x));
  return x;
}

// v_max3_f32: value-identical to nested fmaxf for finite inputs (max is
// exact). Compiler won't form max3 without nnan, so emit directly.
__device__ __forceinline__ float max3f(float a, float b, float c) {
  float d;
  asm("v_max3_f32 %0, %1, %2, %3" : "=v"(d) : "v"(a), "v"(b), "v"(c));
  return d;
}

// Prep: pack per-code {e0, e1, e2, h} where h = -0.5f*c and
// c = ((e0*e0+e1*e1)+e2*e2) rounded exactly like numpy (each product/sum
// individually rounded f32). h is an exact scale of c (exponent shift),
// so c = -2*h is recoverable bit-exactly. Also zero the loss slot.
// (Validated bit-exact in R10: absmax 0.0.)
__global__ __launch_bounds__(256) void vq_prep_kernel(
    const float* __restrict__ cb, float4* __restrict__ cw,
    float* __restrict__ loss_slot) {
  int j = blockIdx.x * 256 + threadIdx.x;
  if (j == 0) *loss_slot = 0.0f;
  if (j < VOCAB) {
    float e0 = cb[3 * j + 0];
    float e1 = cb[3 * j + 1];
    float e2 = cb[3 * j + 2];
    float p0 = opaque(e0 * e0);
    float p1 = opaque(e1 * e1);
    float p2 = opaque(e2 * e2);
    float c = opaque(opaque(p0 + p1) + p2);
    cw[j] = make_float4(e0, e1, e2, -0.5f * c);
  }
}

// Surrogate scan value: t = x.e - c/2 (3 fma). Exact relation: a - 2T = D.
__device__ __forceinline__ float tval(float x0, float x1, float x2,
                                      float4 cd) {
  return fmaf(x0, cd.x, fmaf(x1, cd.y, fmaf(x2, cd.z, cd.w)));
}

// Bit-exact numpy f32 distance (validated absmax=0.0 R10):
//   m = x.e (fma ascending k, first term single-rounded mul)
//   d = (a - 2m) + c;  c = -2*h exact (fma-contract-safe).
__device__ __forceinline__ float dist_f32(float x0, float x1, float x2,
                                          float a, float4 cd) {
  float m = fmaf(x2, cd.z, fmaf(x1, cd.y, x0 * cd.x));
  return fmaf(-2.0f, m, a) + (-2.0f * cd.w);
}

// Main: 512 blocks x 512 threads; block = 128 points x 8 slices.
// Codebook staged in LDS (64 KB); surrogate scan (3 fma/code) with margin
// certification; bounded cooperative bit-exact fallback. ~80.4 KB LDS ->
// 2 blocks/CU.
__global__ __launch_bounds__(512) void vq_kernel(
    const float* __restrict__ feats, const float4* __restrict__ cw,
    float* __restrict__ out_quant, float* __restrict__ out_idx,
    float* __restrict__ out_loss, int npts) {
  __shared__ float4 sTab[VOCAB];            // 64 KB staged codebook
  __shared__ float sT1[SLICES * PTS];       // 4 KB per-slice best t
  __shared__ float sT2[SLICES * PTS];       // 4 KB per-slice 2nd-best
  __shared__ int sG[SLICES * PTS];          // 4 KB per-slice group base
  __shared__ unsigned long long sSlot[PTS]; // 1 KB fallback (d,idx) keys
  __shared__ int sList[PTS];                // 0.5 KB flagged point ids
  __shared__ int sCount;
  __shared__ double sL[PTS];                // 1 KB loss partials

  const int tid = threadIdx.x;
  const int lane = tid & 63;
  const int s = tid >> 6;                   // slice id (wave-uniform)

  if (tid == 0) sCount = 0;

  // Stage codebook: coalesced float4 copy, 8 per thread.
#pragma unroll
  for (int k = 0; k < VOCAB / 512; ++k) sTab[tid + k * 512] = cw[tid + k * 512];

  const int pbase = blockIdx.x * PTS;
  const int pA = pbase + lane;              // this lane's point 0
  const int pB = pbase + 64 + lane;         // this lane's point 1

  const float a0 = feats[3 * pA + 0], a1 = feats[3 * pA + 1],
              a2 = feats[3 * pA + 2];
  const float b0 = feats[3 * pB + 0], b1 = feats[3 * pB + 1],
              b2 = feats[3 * pB + 2];

  // ||x||^2 exactly as numpy: products rounded, then ((p0+p1)+p2)
  float ap0 = opaque(a0 * a0), ap1 = opaque(a1 * a1), ap2 = opaque(a2 * a2);
  const float na = opaque(opaque(ap0 + ap1) + ap2);
  float bp0 = opaque(b0 * b0), bp1 = opaque(b1 * b1), bp2 = opaque(b2 * b2);
  const float nb = opaque(opaque(bp0 + bp1) + bp2);

  __syncthreads();  // staging complete

  const float4* cs = sTab + s * SLICE;

  // Phase 1: surrogate max-scan, 2 points per lane, codes via LDS broadcast.
  // Stream-track best group (t1,g) and second-best group-max t2 per point.
  float t1A = -3.4e38f, t2A = -3.4e38f, t1B = -3.4e38f, t2B = -3.4e38f;
  int gA = 0, gB = 0;
#pragma unroll 2
  for (int g = 0; g < NGRP; ++g) {
    const float4* gp = cs + g * GRP;  // same addr all lanes -> broadcast
    float4 c0 = gp[0], c1 = gp[1], c2 = gp[2], c3 = gp[3];
    float4 c4 = gp[4], c5 = gp[5], c6 = gp[6], c7 = gp[7];
    float uA0 = tval(a0, a1, a2, c0), uB0 = tval(b0, b1, b2, c0);
    float uA1 = tval(a0, a1, a2, c1), uB1 = tval(b0, b1, b2, c1);
    float uA2 = tval(a0, a1, a2, c2), uB2 = tval(b0, b1, b2, c2);
    float uA3 = tval(a0, a1, a2, c3), uB3 = tval(b0, b1, b2, c3);
    float uA4 = tval(a0, a1, a2, c4), uB4 = tval(b0, b1, b2, c4);
    float uA5 = tval(a0, a1, a2, c5), uB5 = tval(b0, b1, b2, c5);
    float uA6 = tval(a0, a1, a2, c6), uB6 = tval(b0, b1, b2, c6);
    float uA7 = tval(a0, a1, a2, c7), uB7 = tval(b0, b1, b2, c7);
    float gmA = max3f(max3f(uA0, uA1, uA2), max3f(uA3, uA4, uA5),
                      fmaxf(uA6, uA7));
    float gmB = max3f(max3f(uB0, uB1, uB2), max3f(uB3, uB4, uB5),
                      fmaxf(uB6, uB7));
    t2A = fmaxf(t2A, fminf(t1A, gmA));  // streaming top-2 of group maxes
    if (gmA > t1A) gA = g;              // strict >: earliest group kept
    t1A = fmaxf(t1A, gmA);
    t2B = fmaxf(t2B, fminf(t1B, gmB));
    if (gmB > t1B) gB = g;
    t1B = fmaxf(t1B, gmB);
  }
  sT1[s * PTS + lane] = t1A;
  sT2[s * PTS + lane] = t2A;
  sG[s * PTS + lane] = s * SLICE + gA * GRP;
  sT1[s * PTS + 64 + lane] = t1B;
  sT2[s * PTS + 64 + lane] = t2B;
  sG[s * PTS + 64 + lane] = s * SLICE + gB * GRP;
  __syncthreads();

  // Epilogue combine: thread tid < 128 owns block-point pt == tid (its own
  // registers: wave 0 -> A point, wave 1 -> B point).
  int bi = 0;
  float q0 = 0.0f, q1 = 0.0f, q2 = 0.0f;
  bool flagged = false;
  const float x0 = (s == 0) ? a0 : b0;
  const float x1 = (s == 0) ? a1 : b1;
  const float x2 = (s == 0) ? a2 : b2;
  const float a = (s == 0) ? na : nb;
  if (tid < PTS) {
    float t1 = sT1[tid], t2 = sT2[tid];
    int gbase = sG[tid];
#pragma unroll
    for (int k = 1; k < SLICES; ++k) {  // ascending slice order
      float u1 = sT1[k * PTS + tid];
      float u2 = sT2[k * PTS + tid];
      t2 = fmaxf(fmaxf(t2, u2), fminf(t1, u1));
      if (u1 > t1) gbase = sG[k * PTS + tid];
      t1 = fmaxf(t1, u1);
    }
    // Margin test (validated R10): if best group's t beats every other
    // group's max by more than worst-case surrogate-vs-numpy skew, the ref
    // argmin is inside gbase. eps = a*2^-21 + 2^-20 (2x safe).
    float eps = fmaf(a, 0x1p-21f, 0x1p-20f);
    flagged = !((t1 - t2) > eps);
    if (flagged) {
      int pos = atomicAdd(&sCount, 1);
      sList[pos] = tid;
      sSlot[tid] = ~0ULL;
    } else {
      // Bit-exact rescan of the certified 8-code group; ascending, strict
      // <: np.argmin first-occurrence.
      float bd = 3.4e38f;
#pragma unroll
      for (int k = 0; k < GRP; ++k) {
        float4 cd = cw[gbase + k];
        float d = dist_f32(x0, x1, x2, a, cd);
        if (d < bd) { bd = d; bi = gbase + k; q0 = cd.x; q1 = cd.y; q2 = cd.z; }
      }
    }
  }
  __syncthreads();

  // Phase 2: cooperative bit-exact full rescan for flagged points.
  // All 512 threads split the 4096 codes (8 each); reduce via sortable
  // (d,idx) key: min key == min d, tie -> min idx (first occurrence).
  const int cnt = sCount;
  for (int f = 0; f < cnt; ++f) {
    const int fpt = sList[f];
    const int fp = pbase + fpt;
    float y0 = feats[3 * fp + 0];   // same addr all threads -> broadcast
    float y1 = feats[3 * fp + 1];
    float y2 = feats[3 * fp + 2];
    float yp0 = opaque(y0 * y0);
    float yp1 = opaque(y1 * y1);
    float yp2 = opaque(y2 * y2);
    float ay = opaque(opaque(yp0 + yp1) + yp2);
    float bd = 3.4e38f;
    int bj = 0;
#pragma unroll
    for (int k = 0; k < 8; ++k) {
      float4 cd = cw[tid * 8 + k];
      float d = dist_f32(y0, y1, y2, ay, cd);
      if (d < bd) { bd = d; bj = tid * 8 + k; }
    }
    unsigned b = __float_as_uint(bd);
    b = (b & 0x80000000u) ? ~b : (b | 0x80000000u);  // total-order transform
    unsigned long long key = ((unsigned long long)b << 32) | (unsigned)bj;
#pragma unroll
    for (int off = 1; off < 64; off <<= 1) {         // wave min-butterfly
      unsigned long long o = __shfl_xor(key, off);
      key = (o < key) ? o : key;
    }
    if (lane == 0) atomicMin(&sSlot[fpt], key);      // 8 atomics/point
  }
  __syncthreads();

  if (tid < PTS) {
    if (flagged) {
      bi = (int)(unsigned)(sSlot[tid] & 0xFFFFFFFFu);
      float4 cd = cw[bi];
      q0 = cd.x; q1 = cd.y; q2 = cd.z;
    }
    const int p = pbase + tid;
    // straight-through: t = q - x (f32), out = x + t (f32), like reference
    float t0 = q0 - x0, t1d = q1 - x1, t2d = q2 - x2;
    out_quant[3 * p + 0] = x0 + t0;
    out_quant[3 * p + 1] = x1 + t1d;
    out_quant[3 * p + 2] = x2 + t2d;
    out_idx[p] = (float)bi;
    sL[tid] = (double)t0 * t0 + (double)t1d * t1d + (double)t2d * t2d;
  }
  __syncthreads();

  if (tid == 0) {
    double acc = 0.0;
#pragma unroll 8
    for (int k = 0; k < PTS; ++k) acc += sL[k];
    // loss = mean((q-x)^2) + 0.25*mean((x-q)^2) = 1.25 * sum / (npts*3)
    atomicAdd(out_loss, (float)(acc * (1.25 / ((double)npts * 3.0))));
  }
}

extern "C" void kernel_launch(void* const* d_in, const int* in_sizes, int n_in,
                              void* d_out, int out_size, void* d_ws,
                              size_t ws_size, hipStream_t stream) {
  const float* feats = (const float*)d_in[0];      // (B*L, 3) f32
  const float* cb = (const float*)d_in[1];         // (4096, 3) f32
  const int npts = in_sizes[0] / 3;                // 65536

  float* out = (float*)d_out;
  float* out_quant = out;                          // npts*3 elems
  float* out_idx = out + in_sizes[0];              // npts elems
  float* out_loss = out + in_sizes[0] + npts;      // 1 elem

  float4* cw = (float4*)d_ws;                      // 4096 * 16 B = 64 KB

  vq_prep_kernel<<<VOCAB / 256, 256, 0, stream>>>(cb, cw, out_loss);
  vq_kernel<<<npts / PTS, 512, 0, stream>>>(feats, cw, out_quant, out_idx,
                                            out_loss, npts);
}